// Round 4
// baseline (14158.270 us; speedup 1.0000x reference)
//
#include <hip/hip_runtime.h>
#include <hip/hip_fp16.h>

// LightGCN, destination-stationary formulation.
// Row space: padded combined [0,UA) users (UA=roundup(U,64)), [UA,UA+I) items.
// Build: chunked counting-sort of 2E (dst,src,w) entries into 64-row buckets,
//        per-chunk regions (no global atomics, sequential writes).
// SpMM:  one block per bucket, 32KB LDS fp32 accumulator, ds_add_f32,
//        fp16 sources, software-pipelined gathers. Epilogues fused.

#define D 128
#define CHUNK 16384
#define SRCMASK 0x3FFFF

// ---- quantize fp32 inputs into padded combined fp16 buffer h0 ----
__global__ void k_quant(const float* __restrict__ ue, const float* __restrict__ ie,
                        __half* __restrict__ h0, int U, int UA, int NP) {
    int stride = gridDim.x * blockDim.x;
    int total4 = NP * (D / 4);
    for (int idx = blockIdx.x * blockDim.x + threadIdx.x; idx < total4; idx += stride) {
        int g = idx >> 5;            // 32 float4 per row
        int c4 = (idx & 31) * 4;
        float4 v;
        if (g < U)        v = *(const float4*)(ue + (size_t)g * D + c4);
        else if (g >= UA) v = *(const float4*)(ie + (size_t)(g - UA) * D + c4);
        else              v = make_float4(0.f, 0.f, 0.f, 0.f);
        union { __half2 h[2]; uint2 u; } pk;
        pk.h[0] = __floats2half2_rn(v.x, v.y);
        pk.h[1] = __floats2half2_rn(v.z, v.w);
        *(uint2*)(h0 + (size_t)g * D + c4) = pk.u;
    }
}

// ---- K1: per-chunk bucket histogram (LDS atomics only) ----
__global__ __launch_bounds__(256) void k_count(const int* __restrict__ eu,
                                               const int* __restrict__ ei,
                                               int* __restrict__ C, int E, int NB, int UA) {
    extern __shared__ int hist[];
    for (int k = threadIdx.x; k < NB; k += blockDim.x) hist[k] = 0;
    __syncthreads();
    int base = blockIdx.x * CHUNK;
    int n = min(CHUNK, E - base);
    for (int t = threadIdx.x; t < n; t += blockDim.x) {
        int u = eu[base + t];
        int i = ei[base + t];
        atomicAdd(&hist[u >> 6], 1);
        atomicAdd(&hist[(UA + i) >> 6], 1);
    }
    __syncthreads();
    int* Crow = C + (size_t)blockIdx.x * NB;
    for (int k = threadIdx.x; k < NB; k += blockDim.x) Crow[k] = hist[k];
}

// ---- K2: per-chunk scan of C-row + bucket-grouped scatter into chunk region ----
__global__ __launch_bounds__(256) void k_scatter(
    const int* __restrict__ eu, const int* __restrict__ ei, const float* __restrict__ w,
    const int* __restrict__ C, int* __restrict__ ptr, uint2* __restrict__ entries,
    int E, int NB, int UA) {
    extern __shared__ int lds[];
    int* cursor  = lds;        // NB ints
    int* partial = lds + NB;   // 256 ints
    int c = blockIdx.x;
    int t = threadIdx.x;
    const int* Crow = C + (size_t)c * NB;
    int CH = (NB + 255) >> 8;
    int c0 = min(t * CH, NB), c1 = min(c0 + CH, NB);
    int sum = 0;
    for (int k = c0; k < c1; ++k) sum += Crow[k];
    partial[t] = sum;
    __syncthreads();
    for (int s = 1; s < 256; s <<= 1) {
        int add = (t >= s) ? partial[t - s] : 0;
        __syncthreads();
        partial[t] += add;
        __syncthreads();
    }
    int base = c * 2 * CHUNK;
    int run = (t == 0 ? 0 : partial[t - 1]) + base;
    int* ptrRow = ptr + (size_t)c * (NB + 1);
    for (int k = c0; k < c1; ++k) {
        cursor[k] = run;
        ptrRow[k] = run;
        run += Crow[k];
    }
    int ebase = c * CHUNK;
    int n = min(CHUNK, E - ebase);
    if (t == 0) ptrRow[NB] = base + 2 * n;
    __syncthreads();
    for (int k = t; k < n; k += blockDim.x) {
        int u = eu[ebase + k];
        int gi = UA + ei[ebase + k];
        unsigned wb = __float_as_uint(w[ebase + k]);
        int pA = atomicAdd(&cursor[u >> 6], 1);               // dst=user, src=item
        entries[pA] = make_uint2((unsigned)((u & 63) << 18) | (unsigned)gi, wb);
        int pB = atomicAdd(&cursor[gi >> 6], 1);              // dst=item, src=user
        entries[pB] = make_uint2((unsigned)((gi & 63) << 18) | (unsigned)u, wb);
    }
}

// ---- bucket-stationary SpMM. MODE 0: write nxt fp16. MODE 1: fused final epilogue.
template <int MODE>
__global__ __launch_bounds__(512, 8) void k_spmm(
    const __half* __restrict__ src, __half* __restrict__ nxt,
    const float* __restrict__ ue, const float* __restrict__ ie,
    const __half* __restrict__ e1h, const __half* __restrict__ e2h,
    float* __restrict__ out,
    const int* __restrict__ ptr, const uint2* __restrict__ entries,
    int NB, int NC, int U, int UA, int NP) {
    __shared__ float accum[64 * D];
    for (int k = threadIdx.x; k < 64 * D; k += blockDim.x) accum[k] = 0.f;
    __syncthreads();
    int b = blockIdx.x;
    int unit = threadIdx.x >> 6;
    int lane = threadIdx.x & 63;
    for (int c = unit; c < NC; c += 8) {
        const int* pr = ptr + (size_t)c * (NB + 1) + b;
        int k0 = pr[0], k1 = pr[1];
        int len = k1 - k0;
        if (len <= 0) continue;
        const uint2* seg = entries + k0;
        // depth-2 software pipeline: entry prefetch + gathers issued 1 iter ahead
        uint2 eA = seg[0];
        uint2 eB = (len > 1) ? seg[1] : eA;
        const __half* pA = src + (size_t)(eA.x & SRCMASK) * D;
        __half a0 = pA[lane];
        __half a1 = pA[lane + 64];
        float wA = __uint_as_float(eA.y);
        int dA = (int)(eA.x >> 18);
        for (int j = 0; j < len; ++j) {
            uint2 eC = seg[min(j + 2, len - 1)];
            const __half* pB = src + (size_t)(eB.x & SRCMASK) * D;
            __half b0 = pB[lane];
            __half b1 = pB[lane + 64];
            float wB = __uint_as_float(eB.y);
            int dB = (int)(eB.x >> 18);
            atomicAdd(&accum[dA * D + lane],      wA * __half2float(a0));
            atomicAdd(&accum[dA * D + 64 + lane], wA * __half2float(a1));
            a0 = b0; a1 = b1; wA = wB; dA = dB; eB = eC;
        }
    }
    __syncthreads();
    int rowBase = b * 64;
    if (MODE == 0) {
        for (int idx = threadIdx.x; idx < 64 * (D / 2); idx += blockDim.x) {
            int r = idx >> 6;
            int c2 = (idx & 63) * 2;
            int g = rowBase + r;
            if (g >= NP) continue;
            __half2 h = __floats2half2_rn(accum[r * D + c2], accum[r * D + c2 + 1]);
            *(__half2*)(nxt + (size_t)g * D + c2) = h;
        }
    } else {
        for (int idx = threadIdx.x; idx < 64 * (D / 4); idx += blockDim.x) {
            int r = idx >> 5;
            int c4 = (idx & 31) * 4;
            int g = rowBase + r;
            const float* e0p;
            int outRow;
            if (g < U)                     { outRow = g;             e0p = ue + (size_t)g * D + c4; }
            else if (g >= UA && g < NP)    { outRow = U + (g - UA);  e0p = ie + (size_t)(g - UA) * D + c4; }
            else continue;
            float4 s = *(const float4*)&accum[r * D + c4];
            float4 e0 = *(const float4*)e0p;
            uint2 r1 = *(const uint2*)(e1h + (size_t)g * D + c4);
            uint2 r2 = *(const uint2*)(e2h + (size_t)g * D + c4);
            float2 f1a = __half22float2(*(__half2*)&r1.x);
            float2 f1b = __half22float2(*(__half2*)&r1.y);
            float2 f2a = __half22float2(*(__half2*)&r2.x);
            float2 f2b = __half22float2(*(__half2*)&r2.y);
            float4 o;
            o.x = 0.25f * (e0.x + f1a.x + f2a.x + s.x);
            o.y = 0.25f * (e0.y + f1a.y + f2a.y + s.y);
            o.z = 0.25f * (e0.z + f1b.x + f2b.x + s.z);
            o.w = 0.25f * (e0.w + f1b.y + f2b.y + s.w);
            *(float4*)(out + (size_t)outRow * D + c4) = o;
        }
    }
}

extern "C" void kernel_launch(void* const* d_in, const int* in_sizes, int n_in,
                              void* d_out, int out_size, void* d_ws, size_t ws_size,
                              hipStream_t stream) {
    const float* ue = (const float*)d_in[0];
    const float* ie = (const float*)d_in[1];
    const float* w  = (const float*)d_in[2];
    const int*   eu = (const int*)d_in[3];
    const int*   ei = (const int*)d_in[4];
    // n_layers fixed at 3 by the reference setup.

    const int U  = in_sizes[0] / D;
    const int I  = in_sizes[1] / D;
    const int E  = in_sizes[2];
    const int UA = ((U + 63) >> 6) << 6;
    const int NP = UA + I;
    const int NB = (NP + 63) >> 6;
    const int NC = (E + CHUNK - 1) / CHUNK;

    // ws layout: h0 | e1h | e2h | entries | C | ptr
    __half* h0  = (__half*)d_ws;
    __half* e1h = h0 + (size_t)NP * D;
    __half* e2h = e1h + (size_t)NP * D;
    uint2* entries = (uint2*)(e2h + (size_t)NP * D);
    int* C   = (int*)(entries + (size_t)NC * 2 * CHUNK);
    int* ptr = C + (size_t)NC * NB;

    const size_t needed = (size_t)NP * D * 2 * 3
                        + (size_t)NC * 2 * CHUNK * 8
                        + (size_t)NC * NB * 4
                        + (size_t)NC * (NB + 1) * 4;
    if (ws_size < needed) return;

    k_quant<<<2048, 256, 0, stream>>>(ue, ie, h0, U, UA, NP);
    k_count<<<NC, 256, (size_t)NB * 4, stream>>>(eu, ei, C, E, NB, UA);
    k_scatter<<<NC, 256, (size_t)(NB + 256) * 4, stream>>>(eu, ei, w, C, ptr, entries, E, NB, UA);

    k_spmm<0><<<NB, 512, 0, stream>>>(h0,  e1h, ue, ie, nullptr, nullptr, nullptr,
                                      ptr, entries, NB, NC, U, UA, NP);
    k_spmm<0><<<NB, 512, 0, stream>>>(e1h, e2h, ue, ie, nullptr, nullptr, nullptr,
                                      ptr, entries, NB, NC, U, UA, NP);
    k_spmm<1><<<NB, 512, 0, stream>>>(e2h, nullptr, ue, ie, e1h, e2h, (float*)d_out,
                                      ptr, entries, NB, NC, U, UA, NP);
}

// Round 5
// 917.192 us; speedup vs baseline: 15.4365x; 15.4365x over previous
//
#include <hip/hip_runtime.h>
#include <hip/hip_fp16.h>

// LightGCN: pull-CSR SpMM (32 lanes/row, register accumulation, fp16 sources)
// + atomic-free chunked counting-sort CSR build.
// Padded combined row space: [0,U) users, [UA, UA+I) items, UA=roundup(U,64).
// Entry: x = (dstLocal6 << 18) | srcGlobal18, y = fp32 weight bits.

#define D 128
#define CHUNK 16384
#define SRCMASK 0x3FFFF

// ---- quantize fp32 inputs into padded combined fp16 buffer h0 ----
__global__ void k_quant(const float* __restrict__ ue, const float* __restrict__ ie,
                        __half* __restrict__ h0, int U, int UA, int NP) {
    int stride = gridDim.x * blockDim.x;
    int total4 = NP * (D / 4);
    for (int idx = blockIdx.x * blockDim.x + threadIdx.x; idx < total4; idx += stride) {
        int g = idx >> 5;
        int c4 = (idx & 31) * 4;
        float4 v;
        if (g < U)        v = *(const float4*)(ue + (size_t)g * D + c4);
        else if (g >= UA) v = *(const float4*)(ie + (size_t)(g - UA) * D + c4);
        else              v = make_float4(0.f, 0.f, 0.f, 0.f);
        union { __half2 h[2]; uint2 u; } pk;
        pk.h[0] = __floats2half2_rn(v.x, v.y);
        pk.h[1] = __floats2half2_rn(v.z, v.w);
        *(uint2*)(h0 + (size_t)g * D + c4) = pk.u;
    }
}

// ---- per-chunk bucket histogram (LDS atomics only) -> C[c][b] ----
__global__ __launch_bounds__(256) void k_count(const int* __restrict__ eu,
                                               const int* __restrict__ ei,
                                               int* __restrict__ C, int E, int NB, int UA) {
    extern __shared__ int hist[];
    for (int k = threadIdx.x; k < NB; k += blockDim.x) hist[k] = 0;
    __syncthreads();
    int base = blockIdx.x * CHUNK;
    int n = min(CHUNK, E - base);
    for (int t = threadIdx.x; t < n; t += blockDim.x) {
        int u = eu[base + t];
        int i = ei[base + t];
        atomicAdd(&hist[u >> 6], 1);
        atomicAdd(&hist[(UA + i) >> 6], 1);
    }
    __syncthreads();
    int* Crow = C + (size_t)blockIdx.x * NB;
    for (int k = threadIdx.x; k < NB; k += blockDim.x) Crow[k] = hist[k];
}

// ---- bucket totals: T[b] = sum_c C[c][b] (coalesced column sums) ----
__global__ void k_btot(const int* __restrict__ C, int* __restrict__ T, int NB, int NC) {
    int b = blockIdx.x * blockDim.x + threadIdx.x;
    if (b >= NB) return;
    int s = 0;
    for (int c = 0; c < NC; ++c) s += C[(size_t)c * NB + b];
    T[b] = s;
}

// ---- single-block exclusive scan of T -> offb[0..NB] ----
__global__ __launch_bounds__(1024) void k_scan(const int* __restrict__ T,
                                               int* __restrict__ offb, int N) {
    __shared__ int partial[1024];
    int t = threadIdx.x;
    int CH = (N + 1023) >> 10;
    int c0 = min(t * CH, N), c1 = min(c0 + CH, N);
    int sum = 0;
    for (int k = c0; k < c1; ++k) sum += T[k];
    partial[t] = sum;
    __syncthreads();
    for (int s = 1; s < 1024; s <<= 1) {
        int add = (t >= s) ? partial[t - s] : 0;
        __syncthreads();
        partial[t] += add;
        __syncthreads();
    }
    int run = (t == 0) ? 0 : partial[t - 1];
    for (int k = c0; k < c1; ++k) { offb[k] = run; run += T[k]; }
    if (t == 0) offb[N] = partial[1023];
}

// ---- colScan[c][b] = offb[b] + prefix_{c'<c} C[c'][b] ----
__global__ void k_colscan(const int* __restrict__ C, const int* __restrict__ offb,
                          int* __restrict__ colScan, int NB, int NC) {
    int b = blockIdx.x * blockDim.x + threadIdx.x;
    if (b >= NB) return;
    int run = offb[b];
    for (int c = 0; c < NC; ++c) {
        size_t k = (size_t)c * NB + b;
        colScan[k] = run;
        run += C[k];
    }
}

// ---- scatter entries directly to final bucket-grouped positions ----
__global__ __launch_bounds__(256) void k_cscatter(
    const int* __restrict__ eu, const int* __restrict__ ei, const float* __restrict__ w,
    const int* __restrict__ colScan, uint2* __restrict__ entA, int E, int NB, int UA) {
    extern __shared__ int cursor[];
    int c = blockIdx.x, t = threadIdx.x;
    const int* cs = colScan + (size_t)c * NB;
    for (int k = t; k < NB; k += 256) cursor[k] = cs[k];
    __syncthreads();
    int base = c * CHUNK;
    int n = min(CHUNK, E - base);
    for (int k = t; k < n; k += 256) {
        int u = eu[base + k];
        int gi = UA + ei[base + k];
        unsigned wb = __float_as_uint(w[base + k]);
        int pA = atomicAdd(&cursor[u >> 6], 1);
        entA[pA] = make_uint2(((unsigned)(u & 63) << 18) | (unsigned)gi, wb);
        int pB = atomicAdd(&cursor[gi >> 6], 1);
        entA[pB] = make_uint2(((unsigned)(gi & 63) << 18) | (unsigned)u, wb);
    }
}

// ---- per-bucket counting sort by row -> row-grouped CSR + off[] ----
__global__ __launch_bounds__(256) void k_rowsort(
    const uint2* __restrict__ entA, uint2* __restrict__ entB,
    const int* __restrict__ offb, int* __restrict__ off, int NP) {
    __shared__ int hist[64];
    __shared__ int rowOff[64];
    __shared__ int cursor[64];
    int b = blockIdx.x, t = threadIdx.x;
    int segBase = offb[b];
    int len = offb[b + 1] - segBase;
    if (t < 64) hist[t] = 0;
    __syncthreads();
    for (int k = t; k < len; k += 256)
        atomicAdd(&hist[entA[segBase + k].x >> 18], 1);
    __syncthreads();
    if (t == 0) {
        int run = 0;
        for (int r = 0; r < 64; ++r) { rowOff[r] = run; cursor[r] = run; run += hist[r]; }
    }
    __syncthreads();
    for (int k = t; k < len; k += 256) {
        uint2 e = entA[segBase + k];
        int p = atomicAdd(&cursor[e.x >> 18], 1);
        entB[segBase + p] = e;
    }
    if (t < 64) {
        int g = b * 64 + t;
        if (g <= NP) off[g] = segBase + rowOff[t];
    }
}

__device__ inline void acc_h4(float4& s, uint2 raw, float wv) {
    float2 fa = __half22float2(*(__half2*)&raw.x);
    float2 fb = __half22float2(*(__half2*)&raw.y);
    s.x += wv * fa.x; s.y += wv * fa.y; s.z += wv * fb.x; s.w += wv * fb.y;
}

// ---- pull-SpMM: 32 lanes per row, 4-way unrolled fp16 gathers ----
// MODE 0: store fp16 into nxt. MODE 1: fused epilogue out = .25*(e0+e1+e2+s).
template <int MODE>
__global__ __launch_bounds__(256) void k_spmm(
    const __half* __restrict__ src, __half* __restrict__ nxt,
    const float* __restrict__ ue, const float* __restrict__ ie,
    const __half* __restrict__ e1h, const __half* __restrict__ e2h,
    float* __restrict__ out,
    const int* __restrict__ off, const uint2* __restrict__ csr,
    int U, int UA, int NP) {
    int row = blockIdx.x * 8 + (threadIdx.x >> 5);
    if (row >= NP) return;
    int lane = threadIdx.x & 31;
    int beg = off[row], end = off[row + 1];
    float4 s = make_float4(0.f, 0.f, 0.f, 0.f);
    int p = beg;
    for (; p + 4 <= end; p += 4) {
        uint2 m0 = csr[p], m1 = csr[p + 1], m2 = csr[p + 2], m3 = csr[p + 3];
        uint2 g0 = *(const uint2*)(src + (size_t)(m0.x & SRCMASK) * D + lane * 4);
        uint2 g1 = *(const uint2*)(src + (size_t)(m1.x & SRCMASK) * D + lane * 4);
        uint2 g2 = *(const uint2*)(src + (size_t)(m2.x & SRCMASK) * D + lane * 4);
        uint2 g3 = *(const uint2*)(src + (size_t)(m3.x & SRCMASK) * D + lane * 4);
        acc_h4(s, g0, __uint_as_float(m0.y));
        acc_h4(s, g1, __uint_as_float(m1.y));
        acc_h4(s, g2, __uint_as_float(m2.y));
        acc_h4(s, g3, __uint_as_float(m3.y));
    }
    for (; p < end; ++p) {
        uint2 m0 = csr[p];
        uint2 g0 = *(const uint2*)(src + (size_t)(m0.x & SRCMASK) * D + lane * 4);
        acc_h4(s, g0, __uint_as_float(m0.y));
    }
    size_t o = (size_t)row * D + lane * 4;
    if (MODE == 0) {
        union { __half2 h[2]; uint2 u; } pk;
        pk.h[0] = __floats2half2_rn(s.x, s.y);
        pk.h[1] = __floats2half2_rn(s.z, s.w);
        *(uint2*)(nxt + o) = pk.u;
    } else {
        int outRow;
        const float* e0p;
        if (row < U)       { outRow = row;            e0p = ue + o; }
        else if (row >= UA){ outRow = U + (row - UA); e0p = ie + (size_t)(row - UA) * D + lane * 4; }
        else return;  // pad row
        float4 e0 = *(const float4*)e0p;
        uint2 r1 = *(const uint2*)(e1h + o);
        uint2 r2 = *(const uint2*)(e2h + o);
        float2 f1a = __half22float2(*(__half2*)&r1.x);
        float2 f1b = __half22float2(*(__half2*)&r1.y);
        float2 f2a = __half22float2(*(__half2*)&r2.x);
        float2 f2b = __half22float2(*(__half2*)&r2.y);
        float4 r;
        r.x = 0.25f * (e0.x + f1a.x + f2a.x + s.x);
        r.y = 0.25f * (e0.y + f1a.y + f2a.y + s.y);
        r.z = 0.25f * (e0.z + f1b.x + f2b.x + s.z);
        r.w = 0.25f * (e0.w + f1b.y + f2b.y + s.w);
        *(float4*)(out + (size_t)outRow * D + lane * 4) = r;
    }
}

extern "C" void kernel_launch(void* const* d_in, const int* in_sizes, int n_in,
                              void* d_out, int out_size, void* d_ws, size_t ws_size,
                              hipStream_t stream) {
    const float* ue = (const float*)d_in[0];
    const float* ie = (const float*)d_in[1];
    const float* w  = (const float*)d_in[2];
    const int*   eu = (const int*)d_in[3];
    const int*   ei = (const int*)d_in[4];
    // n_layers fixed at 3 by the reference setup.

    const int U  = in_sizes[0] / D;
    const int I  = in_sizes[1] / D;
    const int E  = in_sizes[2];
    const int UA = ((U + 63) >> 6) << 6;
    const int NP = UA + I;
    const int NB = (NP + 63) >> 6;
    const int NC = (E + CHUNK - 1) / CHUNK;
    const size_t nE2 = (size_t)2 * E;

    // ws: h0 | e1h | e2h | entB | C | colScan | T | offb | off   (entA aliases e1h/e2h)
    __half* h0   = (__half*)d_ws;
    __half* e1h  = h0 + (size_t)NP * D;
    __half* e2h  = e1h + (size_t)NP * D;
    uint2*  entB = (uint2*)(e2h + (size_t)NP * D);
    int* C       = (int*)(entB + nE2);
    int* colScan = C + (size_t)NC * NB;
    int* T       = colScan + (size_t)NC * NB;
    int* offb    = T + NB;
    int* off     = offb + NB + 1;
    uint2* entA  = (uint2*)e1h;   // dead once k_rowsort finishes

    const size_t needed = (size_t)NP * D * 2 * 3
                        + nE2 * 8
                        + ((size_t)2 * NC * NB + NB + (NB + 1) + (NP + 1)) * 4;
    if (ws_size < needed) return;

    k_quant<<<2048, 256, 0, stream>>>(ue, ie, h0, U, UA, NP);
    k_count<<<NC, 256, (size_t)NB * 4, stream>>>(eu, ei, C, E, NB, UA);
    k_btot<<<(NB + 255) / 256, 256, 0, stream>>>(C, T, NB, NC);
    k_scan<<<1, 1024, 0, stream>>>(T, offb, NB);
    k_colscan<<<(NB + 255) / 256, 256, 0, stream>>>(C, offb, colScan, NB, NC);
    k_cscatter<<<NC, 256, (size_t)NB * 4, stream>>>(eu, ei, w, colScan, entA, E, NB, UA);
    k_rowsort<<<NB, 256, 0, stream>>>(entA, entB, offb, off, NP);

    const int nbS = (NP + 7) / 8;
    k_spmm<0><<<nbS, 256, 0, stream>>>(h0,  e1h, ue, ie, nullptr, nullptr, nullptr,
                                       off, entB, U, UA, NP);
    k_spmm<0><<<nbS, 256, 0, stream>>>(e1h, e2h, ue, ie, nullptr, nullptr, nullptr,
                                       off, entB, U, UA, NP);
    k_spmm<1><<<nbS, 256, 0, stream>>>(e2h, nullptr, ue, ie, e1h, e2h, (float*)d_out,
                                       off, entB, U, UA, NP);
}

// Round 6
// 901.178 us; speedup vs baseline: 15.7109x; 1.0178x over previous
//
#include <hip/hip_runtime.h>
#include <hip/hip_fp16.h>

// LightGCN: pull-CSR SpMM (16 lanes/row x 16B gathers, 4-way unroll + entry
// prefetch => 16 row-gathers in flight per wave) + atomic-free counting-sort
// CSR build. Padded combined row space: [0,U) users, [UA,UA+I) items.
// Entry: x = (dstLocal6 << 18) | srcGlobal18, y = fp32 weight bits.

#define D 128
#define CHUNK 16384
#define SRCMASK 0x3FFFF

// ---- quantize fp32 inputs into padded combined fp16 buffer h0 ----
__global__ void k_quant(const float* __restrict__ ue, const float* __restrict__ ie,
                        __half* __restrict__ h0, int U, int UA, int NP) {
    int stride = gridDim.x * blockDim.x;
    int total4 = NP * (D / 4);
    for (int idx = blockIdx.x * blockDim.x + threadIdx.x; idx < total4; idx += stride) {
        int g = idx >> 5;
        int c4 = (idx & 31) * 4;
        float4 v;
        if (g < U)        v = *(const float4*)(ue + (size_t)g * D + c4);
        else if (g >= UA) v = *(const float4*)(ie + (size_t)(g - UA) * D + c4);
        else              v = make_float4(0.f, 0.f, 0.f, 0.f);
        union { __half2 h[2]; uint2 u; } pk;
        pk.h[0] = __floats2half2_rn(v.x, v.y);
        pk.h[1] = __floats2half2_rn(v.z, v.w);
        *(uint2*)(h0 + (size_t)g * D + c4) = pk.u;
    }
}

// ---- per-chunk bucket histogram (LDS atomics only) -> C[c][b] ----
__global__ __launch_bounds__(256) void k_count(const int* __restrict__ eu,
                                               const int* __restrict__ ei,
                                               int* __restrict__ C, int E, int NB, int UA) {
    extern __shared__ int hist[];
    for (int k = threadIdx.x; k < NB; k += blockDim.x) hist[k] = 0;
    __syncthreads();
    int base = blockIdx.x * CHUNK;
    int n = min(CHUNK, E - base);
    for (int t = threadIdx.x; t < n; t += blockDim.x) {
        int u = eu[base + t];
        int i = ei[base + t];
        atomicAdd(&hist[u >> 6], 1);
        atomicAdd(&hist[(UA + i) >> 6], 1);
    }
    __syncthreads();
    int* Crow = C + (size_t)blockIdx.x * NB;
    for (int k = threadIdx.x; k < NB; k += blockDim.x) Crow[k] = hist[k];
}

// ---- bucket totals: T[b] = sum_c C[c][b] ----
__global__ void k_btot(const int* __restrict__ C, int* __restrict__ T, int NB, int NC) {
    int b = blockIdx.x * blockDim.x + threadIdx.x;
    if (b >= NB) return;
    int s = 0;
    for (int c = 0; c < NC; ++c) s += C[(size_t)c * NB + b];
    T[b] = s;
}

// ---- single-block exclusive scan of T -> offb[0..NB] ----
__global__ __launch_bounds__(1024) void k_scan(const int* __restrict__ T,
                                               int* __restrict__ offb, int N) {
    __shared__ int partial[1024];
    int t = threadIdx.x;
    int CH = (N + 1023) >> 10;
    int c0 = min(t * CH, N), c1 = min(c0 + CH, N);
    int sum = 0;
    for (int k = c0; k < c1; ++k) sum += T[k];
    partial[t] = sum;
    __syncthreads();
    for (int s = 1; s < 1024; s <<= 1) {
        int add = (t >= s) ? partial[t - s] : 0;
        __syncthreads();
        partial[t] += add;
        __syncthreads();
    }
    int run = (t == 0) ? 0 : partial[t - 1];
    for (int k = c0; k < c1; ++k) { offb[k] = run; run += T[k]; }
    if (t == 0) offb[N] = partial[1023];
}

// ---- colScan[c][b] = offb[b] + prefix_{c'<c} C[c'][b] ----
__global__ void k_colscan(const int* __restrict__ C, const int* __restrict__ offb,
                          int* __restrict__ colScan, int NB, int NC) {
    int b = blockIdx.x * blockDim.x + threadIdx.x;
    if (b >= NB) return;
    int run = offb[b];
    for (int c = 0; c < NC; ++c) {
        size_t k = (size_t)c * NB + b;
        colScan[k] = run;
        run += C[k];
    }
}

// ---- scatter entries directly to final bucket-grouped positions ----
__global__ __launch_bounds__(256) void k_cscatter(
    const int* __restrict__ eu, const int* __restrict__ ei, const float* __restrict__ w,
    const int* __restrict__ colScan, uint2* __restrict__ entA, int E, int NB, int UA) {
    extern __shared__ int cursor[];
    int c = blockIdx.x, t = threadIdx.x;
    const int* cs = colScan + (size_t)c * NB;
    for (int k = t; k < NB; k += 256) cursor[k] = cs[k];
    __syncthreads();
    int base = c * CHUNK;
    int n = min(CHUNK, E - base);
    for (int k = t; k < n; k += 256) {
        int u = eu[base + k];
        int gi = UA + ei[base + k];
        unsigned wb = __float_as_uint(w[base + k]);
        int pA = atomicAdd(&cursor[u >> 6], 1);
        entA[pA] = make_uint2(((unsigned)(u & 63) << 18) | (unsigned)gi, wb);
        int pB = atomicAdd(&cursor[gi >> 6], 1);
        entA[pB] = make_uint2(((unsigned)(gi & 63) << 18) | (unsigned)u, wb);
    }
}

// ---- per-bucket counting sort by row -> row-grouped CSR + off[] ----
__global__ __launch_bounds__(256) void k_rowsort(
    const uint2* __restrict__ entA, uint2* __restrict__ entB,
    const int* __restrict__ offb, int* __restrict__ off, int NP) {
    __shared__ int hist[64];
    __shared__ int rowOff[64];
    __shared__ int cursor[64];
    int b = blockIdx.x, t = threadIdx.x;
    int segBase = offb[b];
    int len = offb[b + 1] - segBase;
    if (t < 64) hist[t] = 0;
    __syncthreads();
    for (int k = t; k < len; k += 256)
        atomicAdd(&hist[entA[segBase + k].x >> 18], 1);
    __syncthreads();
    if (t == 0) {
        int run = 0;
        for (int r = 0; r < 64; ++r) { rowOff[r] = run; cursor[r] = run; run += hist[r]; }
    }
    __syncthreads();
    for (int k = t; k < len; k += 256) {
        uint2 e = entA[segBase + k];
        int p = atomicAdd(&cursor[e.x >> 18], 1);
        entB[segBase + p] = e;
    }
    if (t < 64) {
        int g = b * 64 + t;
        if (g <= NP) off[g] = segBase + rowOff[t];
    }
}

__device__ inline void acc_h8(float4& sa, float4& sb, uint4 raw, float wv) {
    float2 f0 = __half22float2(*(__half2*)&raw.x);
    float2 f1 = __half22float2(*(__half2*)&raw.y);
    float2 f2 = __half22float2(*(__half2*)&raw.z);
    float2 f3 = __half22float2(*(__half2*)&raw.w);
    sa.x += wv * f0.x; sa.y += wv * f0.y; sa.z += wv * f1.x; sa.w += wv * f1.y;
    sb.x += wv * f2.x; sb.y += wv * f2.y; sb.z += wv * f3.x; sb.w += wv * f3.y;
}

// ---- pull-SpMM: 16 lanes per row, 16B gathers, 4-way unroll + entry prefetch.
// MODE 0: store fp16 into nxt. MODE 1: fused epilogue out = .25*(e0+e1+e2+s).
template <int MODE>
__global__ __launch_bounds__(256) void k_spmm(
    const __half* __restrict__ src, __half* __restrict__ nxt,
    const float* __restrict__ ue, const float* __restrict__ ie,
    const __half* __restrict__ e1h, const __half* __restrict__ e2h,
    float* __restrict__ out,
    const int* __restrict__ off, const uint2* __restrict__ csr,
    int U, int UA, int NP) {
    int row = blockIdx.x * 16 + (threadIdx.x >> 4);
    if (row >= NP) return;
    int lane = threadIdx.x & 15;          // 16 lanes x 8 halves = 128
    int beg = off[row], end = off[row + 1];
    float4 sa = make_float4(0.f, 0.f, 0.f, 0.f);
    float4 sb = make_float4(0.f, 0.f, 0.f, 0.f);
    const int h = lane * 8;               // half offset within row (16B)

    int nIter = (end - beg) >> 2;
    int p = beg;
    if (nIter > 0) {
        uint2 m0 = csr[p], m1 = csr[p + 1], m2 = csr[p + 2], m3 = csr[p + 3];
        for (int it = 0; it < nIter; ++it) {
            // issue all 4 independent row-gathers
            uint4 g0 = *(const uint4*)(src + (size_t)(m0.x & SRCMASK) * D + h);
            uint4 g1 = *(const uint4*)(src + (size_t)(m1.x & SRCMASK) * D + h);
            uint4 g2 = *(const uint4*)(src + (size_t)(m2.x & SRCMASK) * D + h);
            uint4 g3 = *(const uint4*)(src + (size_t)(m3.x & SRCMASK) * D + h);
            float w0 = __uint_as_float(m0.y), w1 = __uint_as_float(m1.y);
            float w2 = __uint_as_float(m2.y), w3 = __uint_as_float(m3.y);
            // prefetch next iteration's entries while gathers are in flight
            int pn = p + 4;
            if (it + 1 < nIter) {
                m0 = csr[pn]; m1 = csr[pn + 1]; m2 = csr[pn + 2]; m3 = csr[pn + 3];
            }
            acc_h8(sa, sb, g0, w0);
            acc_h8(sa, sb, g1, w1);
            acc_h8(sa, sb, g2, w2);
            acc_h8(sa, sb, g3, w3);
            p = pn;
        }
    }
    for (; p < end; ++p) {
        uint2 m = csr[p];
        uint4 g = *(const uint4*)(src + (size_t)(m.x & SRCMASK) * D + h);
        acc_h8(sa, sb, g, __uint_as_float(m.y));
    }

    size_t o = (size_t)row * D + h;
    if (MODE == 0) {
        union { __half2 hh[4]; uint4 u; } pk;
        pk.hh[0] = __floats2half2_rn(sa.x, sa.y);
        pk.hh[1] = __floats2half2_rn(sa.z, sa.w);
        pk.hh[2] = __floats2half2_rn(sb.x, sb.y);
        pk.hh[3] = __floats2half2_rn(sb.z, sb.w);
        *(uint4*)(nxt + o) = pk.u;
    } else {
        int outRow;
        const float* e0p;
        if (row < U)        { outRow = row;            e0p = ue + o; }
        else if (row >= UA) { outRow = U + (row - UA); e0p = ie + (size_t)(row - UA) * D + h; }
        else return;  // pad row
        float4 e0a = *(const float4*)e0p;
        float4 e0b = *(const float4*)(e0p + 4);
        uint4 r1 = *(const uint4*)(e1h + o);
        uint4 r2 = *(const uint4*)(e2h + o);
        float2 f1[4] = { __half22float2(*(__half2*)&r1.x), __half22float2(*(__half2*)&r1.y),
                         __half22float2(*(__half2*)&r1.z), __half22float2(*(__half2*)&r1.w) };
        float2 f2[4] = { __half22float2(*(__half2*)&r2.x), __half22float2(*(__half2*)&r2.y),
                         __half22float2(*(__half2*)&r2.z), __half22float2(*(__half2*)&r2.w) };
        float4 ra, rb;
        ra.x = 0.25f * (e0a.x + f1[0].x + f2[0].x + sa.x);
        ra.y = 0.25f * (e0a.y + f1[0].y + f2[0].y + sa.y);
        ra.z = 0.25f * (e0a.z + f1[1].x + f2[1].x + sa.z);
        ra.w = 0.25f * (e0a.w + f1[1].y + f2[1].y + sa.w);
        rb.x = 0.25f * (e0b.x + f1[2].x + f2[2].x + sb.x);
        rb.y = 0.25f * (e0b.y + f1[2].y + f2[2].y + sb.y);
        rb.z = 0.25f * (e0b.z + f1[3].x + f2[3].x + sb.z);
        rb.w = 0.25f * (e0b.w + f1[3].y + f2[3].y + sb.w);
        float* op = out + (size_t)outRow * D + h;
        *(float4*)op = ra;
        *(float4*)(op + 4) = rb;
    }
}

extern "C" void kernel_launch(void* const* d_in, const int* in_sizes, int n_in,
                              void* d_out, int out_size, void* d_ws, size_t ws_size,
                              hipStream_t stream) {
    const float* ue = (const float*)d_in[0];
    const float* ie = (const float*)d_in[1];
    const float* w  = (const float*)d_in[2];
    const int*   eu = (const int*)d_in[3];
    const int*   ei = (const int*)d_in[4];
    // n_layers fixed at 3 by the reference setup.

    const int U  = in_sizes[0] / D;
    const int I  = in_sizes[1] / D;
    const int E  = in_sizes[2];
    const int UA = ((U + 63) >> 6) << 6;
    const int NP = UA + I;
    const int NB = (NP + 63) >> 6;
    const int NC = (E + CHUNK - 1) / CHUNK;
    const size_t nE2 = (size_t)2 * E;

    // ws: h0 | e1h | e2h | entB | C | colScan | T | offb | off  (entA aliases e1h/e2h)
    __half* h0   = (__half*)d_ws;
    __half* e1h  = h0 + (size_t)NP * D;
    __half* e2h  = e1h + (size_t)NP * D;
    uint2*  entB = (uint2*)(e2h + (size_t)NP * D);
    int* C       = (int*)(entB + nE2);
    int* colScan = C + (size_t)NC * NB;
    int* T       = colScan + (size_t)NC * NB;
    int* offb    = T + NB;
    int* off     = offb + NB + 1;
    uint2* entA  = (uint2*)e1h;   // dead once k_rowsort finishes

    const size_t needed = (size_t)NP * D * 2 * 3
                        + nE2 * 8
                        + ((size_t)2 * NC * NB + NB + (NB + 1) + (NP + 1)) * 4;
    if (ws_size < needed) return;

    k_quant<<<2048, 256, 0, stream>>>(ue, ie, h0, U, UA, NP);
    k_count<<<NC, 256, (size_t)NB * 4, stream>>>(eu, ei, C, E, NB, UA);
    k_btot<<<(NB + 255) / 256, 256, 0, stream>>>(C, T, NB, NC);
    k_scan<<<1, 1024, 0, stream>>>(T, offb, NB);
    k_colscan<<<(NB + 255) / 256, 256, 0, stream>>>(C, offb, colScan, NB, NC);
    k_cscatter<<<NC, 256, (size_t)NB * 4, stream>>>(eu, ei, w, colScan, entA, E, NB, UA);
    k_rowsort<<<NB, 256, 0, stream>>>(entA, entB, offb, off, NP);

    const int nbS = (NP + 15) / 16;
    k_spmm<0><<<nbS, 256, 0, stream>>>(h0,  e1h, ue, ie, nullptr, nullptr, nullptr,
                                       off, entB, U, UA, NP);
    k_spmm<0><<<nbS, 256, 0, stream>>>(e1h, e2h, ue, ie, nullptr, nullptr, nullptr,
                                       off, entB, U, UA, NP);
    k_spmm<1><<<nbS, 256, 0, stream>>>(e2h, nullptr, ue, ie, e1h, e2h, (float*)d_out,
                                       off, entB, U, UA, NP);
}

// Round 7
// 646.414 us; speedup vs baseline: 21.9028x; 1.3941x over previous
//
#include <hip/hip_runtime.h>

// LightGCN: pull-CSR SpMM with int8 row-quantized gather sources.
// All layer embeddings stored as int8 (128 B/row = 1 cache line) + per-row
// fp32 scale. fp32 accumulate; dequant = q * (w_edge * scale[src]).
// Atomic-free counting-sort CSR build (unchanged from R6).
// Padded combined row space: [0,U) users, [UA,UA+I) items, UA=roundup(U,64).
// Entry: x = (dstLocal6 << 18) | srcGlobal18, y = fp32 weight bits.

#define D 128
#define CHUNK 16384
#define SRCMASK 0x3FFFF
#define TPB 256

// ---------- int8 helpers ----------
__device__ inline unsigned pack4(float a, float b, float c, float d, float qs) {
    int q0 = __float2int_rn(a * qs), q1 = __float2int_rn(b * qs);
    int q2 = __float2int_rn(c * qs), q3 = __float2int_rn(d * qs);
    return ((unsigned)(q0 & 255)) | ((unsigned)(q1 & 255) << 8) |
           ((unsigned)(q2 & 255) << 16) | ((unsigned)(q3 & 255) << 24);
}

__device__ inline void acc_q8(float4& sa, float4& sb, uint2 raw, float m) {
    unsigned x = raw.x, y = raw.y;
    sa.x += m * (float)((int)(x << 24) >> 24);
    sa.y += m * (float)((int)(x << 16) >> 24);
    sa.z += m * (float)((int)(x <<  8) >> 24);
    sa.w += m * (float)((int)(x      ) >> 24);
    sb.x += m * (float)((int)(y << 24) >> 24);
    sb.y += m * (float)((int)(y << 16) >> 24);
    sb.z += m * (float)((int)(y <<  8) >> 24);
    sb.w += m * (float)((int)(y      ) >> 24);
}

// ---------- quantize fp32 inputs -> int8 rows + per-row scale ----------
__global__ __launch_bounds__(TPB) void k_quant8(
    const float* __restrict__ ue, const float* __restrict__ ie,
    uint2* __restrict__ h0q, float* __restrict__ sc0, int U, int UA, int NP) {
    int row = blockIdx.x * (TPB / 16) + (threadIdx.x >> 4);
    if (row >= NP) return;
    int lane = threadIdx.x & 15;
    float4 a = make_float4(0.f, 0.f, 0.f, 0.f);
    float4 b = make_float4(0.f, 0.f, 0.f, 0.f);
    const float* p = nullptr;
    if (row < U)        p = ue + (size_t)row * D + lane * 8;
    else if (row >= UA) p = ie + (size_t)(row - UA) * D + lane * 8;
    if (p) { a = *(const float4*)p; b = *(const float4*)(p + 4); }
    float m = fmaxf(fmaxf(fmaxf(fabsf(a.x), fabsf(a.y)), fmaxf(fabsf(a.z), fabsf(a.w))),
                    fmaxf(fmaxf(fabsf(b.x), fabsf(b.y)), fmaxf(fabsf(b.z), fabsf(b.w))));
    for (int d_ = 1; d_ < 16; d_ <<= 1) m = fmaxf(m, __shfl_xor(m, d_));
    float qs = (m > 0.f) ? 127.f / m : 0.f;
    uint2 q;
    q.x = pack4(a.x, a.y, a.z, a.w, qs);
    q.y = pack4(b.x, b.y, b.z, b.w, qs);
    h0q[(size_t)row * 16 + lane] = q;
    if (lane == 0) sc0[row] = m * (1.f / 127.f);
}

// ---------- CSR build (atomic-free counting sort), unchanged ----------
__global__ __launch_bounds__(256) void k_count(const int* __restrict__ eu,
                                               const int* __restrict__ ei,
                                               int* __restrict__ C, int E, int NB, int UA) {
    extern __shared__ int hist[];
    for (int k = threadIdx.x; k < NB; k += blockDim.x) hist[k] = 0;
    __syncthreads();
    int base = blockIdx.x * CHUNK;
    int n = min(CHUNK, E - base);
    for (int t = threadIdx.x; t < n; t += blockDim.x) {
        int u = eu[base + t];
        int i = ei[base + t];
        atomicAdd(&hist[u >> 6], 1);
        atomicAdd(&hist[(UA + i) >> 6], 1);
    }
    __syncthreads();
    int* Crow = C + (size_t)blockIdx.x * NB;
    for (int k = threadIdx.x; k < NB; k += blockDim.x) Crow[k] = hist[k];
}

__global__ void k_btot(const int* __restrict__ C, int* __restrict__ T, int NB, int NC) {
    int b = blockIdx.x * blockDim.x + threadIdx.x;
    if (b >= NB) return;
    int s = 0;
    for (int c = 0; c < NC; ++c) s += C[(size_t)c * NB + b];
    T[b] = s;
}

__global__ __launch_bounds__(1024) void k_scan(const int* __restrict__ T,
                                               int* __restrict__ offb, int N) {
    __shared__ int partial[1024];
    int t = threadIdx.x;
    int CH = (N + 1023) >> 10;
    int c0 = min(t * CH, N), c1 = min(c0 + CH, N);
    int sum = 0;
    for (int k = c0; k < c1; ++k) sum += T[k];
    partial[t] = sum;
    __syncthreads();
    for (int s = 1; s < 1024; s <<= 1) {
        int add = (t >= s) ? partial[t - s] : 0;
        __syncthreads();
        partial[t] += add;
        __syncthreads();
    }
    int run = (t == 0) ? 0 : partial[t - 1];
    for (int k = c0; k < c1; ++k) { offb[k] = run; run += T[k]; }
    if (t == 0) offb[N] = partial[1023];
}

__global__ void k_colscan(const int* __restrict__ C, const int* __restrict__ offb,
                          int* __restrict__ colScan, int NB, int NC) {
    int b = blockIdx.x * blockDim.x + threadIdx.x;
    if (b >= NB) return;
    int run = offb[b];
    for (int c = 0; c < NC; ++c) {
        size_t k = (size_t)c * NB + b;
        colScan[k] = run;
        run += C[k];
    }
}

__global__ __launch_bounds__(256) void k_cscatter(
    const int* __restrict__ eu, const int* __restrict__ ei, const float* __restrict__ w,
    const int* __restrict__ colScan, uint2* __restrict__ entA, int E, int NB, int UA) {
    extern __shared__ int cursor[];
    int c = blockIdx.x, t = threadIdx.x;
    const int* cs = colScan + (size_t)c * NB;
    for (int k = t; k < NB; k += 256) cursor[k] = cs[k];
    __syncthreads();
    int base = c * CHUNK;
    int n = min(CHUNK, E - base);
    for (int k = t; k < n; k += 256) {
        int u = eu[base + k];
        int gi = UA + ei[base + k];
        unsigned wb = __float_as_uint(w[base + k]);
        int pA = atomicAdd(&cursor[u >> 6], 1);
        entA[pA] = make_uint2(((unsigned)(u & 63) << 18) | (unsigned)gi, wb);
        int pB = atomicAdd(&cursor[gi >> 6], 1);
        entA[pB] = make_uint2(((unsigned)(gi & 63) << 18) | (unsigned)u, wb);
    }
}

__global__ __launch_bounds__(256) void k_rowsort(
    const uint2* __restrict__ entA, uint2* __restrict__ entB,
    const int* __restrict__ offb, int* __restrict__ off, int NP) {
    __shared__ int hist[64];
    __shared__ int rowOff[64];
    __shared__ int cursor[64];
    int b = blockIdx.x, t = threadIdx.x;
    int segBase = offb[b];
    int len = offb[b + 1] - segBase;
    if (t < 64) hist[t] = 0;
    __syncthreads();
    for (int k = t; k < len; k += 256)
        atomicAdd(&hist[entA[segBase + k].x >> 18], 1);
    __syncthreads();
    if (t == 0) {
        int run = 0;
        for (int r = 0; r < 64; ++r) { rowOff[r] = run; cursor[r] = run; run += hist[r]; }
    }
    __syncthreads();
    for (int k = t; k < len; k += 256) {
        uint2 e = entA[segBase + k];
        int p = atomicAdd(&cursor[e.x >> 18], 1);
        entB[segBase + p] = e;
    }
    if (t < 64) {
        int g = b * 64 + t;
        if (g <= NP) off[g] = segBase + rowOff[t];
    }
}

// ---------- pull-SpMM on int8 sources ----------
// MODE 0: quantize result -> nxtq + scn. MODE 1: fused epilogue to fp32 out.
template <int MODE>
__global__ __launch_bounds__(TPB) void k_spmm(
    const uint2* __restrict__ q, const float* __restrict__ sc,
    uint2* __restrict__ nxtq, float* __restrict__ scn,
    const uint2* __restrict__ e1q, const float* __restrict__ sc1,
    const uint2* __restrict__ e2q, const float* __restrict__ sc2,
    const float* __restrict__ ue, const float* __restrict__ ie,
    float* __restrict__ out,
    const int* __restrict__ off, const uint2* __restrict__ csr,
    int U, int UA, int NP) {
    int row = blockIdx.x * (TPB / 16) + (threadIdx.x >> 4);
    if (row >= NP) return;
    int lane = threadIdx.x & 15;
    int beg = off[row], end = off[row + 1];
    float4 sa = make_float4(0.f, 0.f, 0.f, 0.f);
    float4 sb = make_float4(0.f, 0.f, 0.f, 0.f);

    int nIter = (end - beg) >> 2;
    int p = beg;
    if (nIter > 0) {
        uint2 m0 = csr[p], m1 = csr[p + 1], m2 = csr[p + 2], m3 = csr[p + 3];
        for (int it = 0; it < nIter; ++it) {
            int s0 = m0.x & SRCMASK, s1 = m1.x & SRCMASK;
            int s2 = m2.x & SRCMASK, s3 = m3.x & SRCMASK;
            uint2 g0 = q[(size_t)s0 * 16 + lane];
            uint2 g1 = q[(size_t)s1 * 16 + lane];
            uint2 g2 = q[(size_t)s2 * 16 + lane];
            uint2 g3 = q[(size_t)s3 * 16 + lane];
            float f0 = __uint_as_float(m0.y) * sc[s0];
            float f1 = __uint_as_float(m1.y) * sc[s1];
            float f2 = __uint_as_float(m2.y) * sc[s2];
            float f3 = __uint_as_float(m3.y) * sc[s3];
            int pn = p + 4;
            if (it + 1 < nIter) {
                m0 = csr[pn]; m1 = csr[pn + 1]; m2 = csr[pn + 2]; m3 = csr[pn + 3];
            }
            acc_q8(sa, sb, g0, f0);
            acc_q8(sa, sb, g1, f1);
            acc_q8(sa, sb, g2, f2);
            acc_q8(sa, sb, g3, f3);
            p = pn;
        }
    }
    for (; p < end; ++p) {
        uint2 m_ = csr[p];
        int s_ = m_.x & SRCMASK;
        uint2 g_ = q[(size_t)s_ * 16 + lane];
        acc_q8(sa, sb, g_, __uint_as_float(m_.y) * sc[s_]);
    }

    if (MODE == 0) {
        float m = fmaxf(fmaxf(fmaxf(fabsf(sa.x), fabsf(sa.y)), fmaxf(fabsf(sa.z), fabsf(sa.w))),
                        fmaxf(fmaxf(fabsf(sb.x), fabsf(sb.y)), fmaxf(fabsf(sb.z), fabsf(sb.w))));
        for (int d_ = 1; d_ < 16; d_ <<= 1) m = fmaxf(m, __shfl_xor(m, d_));
        float qs = (m > 0.f) ? 127.f / m : 0.f;
        uint2 qo;
        qo.x = pack4(sa.x, sa.y, sa.z, sa.w, qs);
        qo.y = pack4(sb.x, sb.y, sb.z, sb.w, qs);
        nxtq[(size_t)row * 16 + lane] = qo;
        if (lane == 0) scn[row] = m * (1.f / 127.f);
    } else {
        int outRow;
        const float* e0p;
        if (row < U)        { outRow = row;            e0p = ue + (size_t)row * D + lane * 8; }
        else if (row >= UA) { outRow = U + (row - UA); e0p = ie + (size_t)(row - UA) * D + lane * 8; }
        else return;  // pad row
        float4 e0a = *(const float4*)e0p;
        float4 e0b = *(const float4*)(e0p + 4);
        uint2 q1 = e1q[(size_t)row * 16 + lane]; float s1r = sc1[row];
        uint2 q2 = e2q[(size_t)row * 16 + lane]; float s2r = sc2[row];
        unsigned x1 = q1.x, y1 = q1.y, x2 = q2.x, y2 = q2.y;
        float4 ra, rb;
        ra.x = 0.25f * (e0a.x + s1r * (float)((int)(x1 << 24) >> 24) + s2r * (float)((int)(x2 << 24) >> 24) + sa.x);
        ra.y = 0.25f * (e0a.y + s1r * (float)((int)(x1 << 16) >> 24) + s2r * (float)((int)(x2 << 16) >> 24) + sa.y);
        ra.z = 0.25f * (e0a.z + s1r * (float)((int)(x1 <<  8) >> 24) + s2r * (float)((int)(x2 <<  8) >> 24) + sa.z);
        ra.w = 0.25f * (e0a.w + s1r * (float)((int)(x1      ) >> 24) + s2r * (float)((int)(x2      ) >> 24) + sa.w);
        rb.x = 0.25f * (e0b.x + s1r * (float)((int)(y1 << 24) >> 24) + s2r * (float)((int)(y2 << 24) >> 24) + sb.x);
        rb.y = 0.25f * (e0b.y + s1r * (float)((int)(y1 << 16) >> 24) + s2r * (float)((int)(y2 << 16) >> 24) + sb.y);
        rb.z = 0.25f * (e0b.z + s1r * (float)((int)(y1 <<  8) >> 24) + s2r * (float)((int)(y2 <<  8) >> 24) + sb.z);
        rb.w = 0.25f * (e0b.w + s1r * (float)((int)(y1      ) >> 24) + s2r * (float)((int)(y2      ) >> 24) + sb.w);
        float* op = out + (size_t)outRow * D + lane * 8;
        *(float4*)op = ra;
        *(float4*)(op + 4) = rb;
    }
}

extern "C" void kernel_launch(void* const* d_in, const int* in_sizes, int n_in,
                              void* d_out, int out_size, void* d_ws, size_t ws_size,
                              hipStream_t stream) {
    const float* ue = (const float*)d_in[0];
    const float* ie = (const float*)d_in[1];
    const float* w  = (const float*)d_in[2];
    const int*   eu = (const int*)d_in[3];
    const int*   ei = (const int*)d_in[4];
    // n_layers fixed at 3 by the reference setup.

    const int U  = in_sizes[0] / D;
    const int I  = in_sizes[1] / D;
    const int E  = in_sizes[2];
    const int UA = ((U + 63) >> 6) << 6;
    const int NP = UA + I;
    const int NB = (NP + 63) >> 6;
    const int NC = (E + CHUNK - 1) / CHUNK;
    const size_t nE2 = (size_t)2 * E;

    // ws: h0q | e1q | e2q | sc0 | sc1 | sc2 | entB | C | colScan | T | offb | off | entA
    uint2* h0q = (uint2*)d_ws;                   // NP*16 uint2 = NP*128 B
    uint2* e1q = h0q + (size_t)NP * 16;
    uint2* e2q = e1q + (size_t)NP * 16;
    float* sc0 = (float*)(e2q + (size_t)NP * 16);
    float* sc1 = sc0 + NP;
    float* sc2 = sc1 + NP;
    uint2* entB = (uint2*)(sc2 + NP);
    int* C       = (int*)(entB + nE2);
    int* colScan = C + (size_t)NC * NB;
    int* T       = colScan + (size_t)NC * NB;
    int* offb    = T + NB;
    int* off     = offb + NB + 1;
    char* tail   = (char*)(off + NP + 1);
    tail += (8 - ((uintptr_t)tail & 7)) & 7;
    uint2* entA  = (uint2*)tail;

    const size_t needed = (size_t)NP * D * 3 + (size_t)NP * 12
                        + nE2 * 8 * 2
                        + ((size_t)2 * NC * NB + NB + (NB + 1) + (NP + 1)) * 4 + 8;
    if (ws_size < needed) return;

    const int nbR = (NP + 15) / 16;

    k_quant8<<<nbR, TPB, 0, stream>>>(ue, ie, h0q, sc0, U, UA, NP);
    k_count<<<NC, 256, (size_t)NB * 4, stream>>>(eu, ei, C, E, NB, UA);
    k_btot<<<(NB + 255) / 256, 256, 0, stream>>>(C, T, NB, NC);
    k_scan<<<1, 1024, 0, stream>>>(T, offb, NB);
    k_colscan<<<(NB + 255) / 256, 256, 0, stream>>>(C, offb, colScan, NB, NC);
    k_cscatter<<<NC, 256, (size_t)NB * 4, stream>>>(eu, ei, w, colScan, entA, E, NB, UA);
    k_rowsort<<<NB, 256, 0, stream>>>(entA, entB, offb, off, NP);

    k_spmm<0><<<nbR, TPB, 0, stream>>>(h0q, sc0, e1q, sc1,
                                       nullptr, nullptr, nullptr, nullptr,
                                       ue, ie, nullptr, off, entB, U, UA, NP);
    k_spmm<0><<<nbR, TPB, 0, stream>>>(e1q, sc1, e2q, sc2,
                                       nullptr, nullptr, nullptr, nullptr,
                                       ue, ie, nullptr, off, entB, U, UA, NP);
    k_spmm<1><<<nbR, TPB, 0, stream>>>(e2q, sc2, nullptr, nullptr,
                                       e1q, sc1, e2q, sc2,
                                       ue, ie, (float*)d_out, off, entB, U, UA, NP);
}